// Round 3
// baseline (1764.212 us; speedup 1.0000x reference)
//
#include <hip/hip_runtime.h>
#include <hip/hip_bf16.h>

#define B_ 2
#define T_ 1024
#define C_ 1024
#define H_ 16
#define N_ 64

__device__ __forceinline__ float sigmoidf_(float x) { return 1.0f / (1.0f + expf(-x)); }
__device__ __forceinline__ float softplusf_(float x) {
  return fmaxf(x, 0.0f) + log1pf(expf(-fabsf(x)));
}

// ---------------- K1: token shift ----------------
__global__ __launch_bounds__(256) void shift_kernel(
    const float* __restrict__ x, const float* __restrict__ tmx,
    float* __restrict__ xx, float* __restrict__ xxx) {
  long idx = (long)blockIdx.x * 256 + threadIdx.x;  // < B*T*C
  int c = (int)(idx & (C_ - 1));
  int t = (int)((idx >> 10) & (T_ - 1));
  float xv = x[idx];
  float xp = (t > 0) ? x[idx - C_] : 0.0f;
  float d = xp - xv;
  xx[idx] = d;
  xxx[idx] = xv + d * tmx[c];
}

// ---------------- tiled GEMM: C = A (fp32 MxK) * W^T (W fp32 NxK) -----------
// act: 0 none, 1 tanh.
__global__ __launch_bounds__(256) void gemm_kernel(
    const float* __restrict__ A, const float* __restrict__ W,
    float* __restrict__ Cf, int M, int N, int K, int act) {
  __shared__ __align__(16) float As[16][72];
  __shared__ __align__(16) float Ws[16][72];
  int tid = threadIdx.x;
  int tx = tid & 15, ty = tid >> 4;
  int m0 = blockIdx.y * 64, n0 = blockIdx.x * 64;
  int lr = tid >> 2;
  int lc = (tid & 3) << 2;
  float acc[4][4] = {};
  for (int k0 = 0; k0 < K; k0 += 16) {
    float4 av = *(const float4*)(A + (long)(m0 + lr) * K + (k0 + lc));
    As[lc + 0][lr] = av.x; As[lc + 1][lr] = av.y;
    As[lc + 2][lr] = av.z; As[lc + 3][lr] = av.w;
    float4 wv = make_float4(0.f, 0.f, 0.f, 0.f);
    int wr = n0 + lr;
    if (wr < N) wv = *(const float4*)(W + (long)wr * K + (k0 + lc));
    Ws[lc + 0][lr] = wv.x; Ws[lc + 1][lr] = wv.y;
    Ws[lc + 2][lr] = wv.z; Ws[lc + 3][lr] = wv.w;
    __syncthreads();
#pragma unroll
    for (int kk = 0; kk < 16; kk++) {
      float4 a4 = *(const float4*)&As[kk][ty << 2];
      float4 b4 = *(const float4*)&Ws[kk][tx << 2];
      float aa[4] = {a4.x, a4.y, a4.z, a4.w};
      float bb[4] = {b4.x, b4.y, b4.z, b4.w};
#pragma unroll
      for (int i = 0; i < 4; i++) {
#pragma unroll
        for (int j = 0; j < 4; j++) acc[i][j] += aa[i] * bb[j];
      }
    }
    __syncthreads();
  }
#pragma unroll
  for (int i = 0; i < 4; i++) {
    int row = m0 + (ty << 2) + i;
#pragma unroll
    for (int j = 0; j < 4; j++) {
      int col = n0 + (tx << 2) + j;
      if (col < N) {
        float vv = acc[i][j];
        if (act == 1) vv = tanhf(vv);
        Cf[(long)row * N + col] = vv;
      }
    }
  }
}

// ---------------- K3: deltas + build xrg/xwa/xk/xv --------------------------
__global__ __launch_bounds__(256) void mix4_kernel(
    const float* __restrict__ x, const float* __restrict__ xx,
    const float* __restrict__ mix, const float* __restrict__ tmaa,
    const float* __restrict__ w2,
    float* __restrict__ xrg, float* __restrict__ xwa,
    float* __restrict__ xk, float* __restrict__ xv) {
  int m = blockIdx.x;
  int tid = threadIdx.x;
  __shared__ float mrow[128];
  if (tid < 128) mrow[tid] = mix[(long)m * 128 + tid];
  __syncthreads();
#pragma unroll
  for (int cc = 0; cc < 4; cc++) {
    int c = tid + (cc << 8);
    long off = (long)m * C_ + c;
    float xb = x[off];
    float xxv = xx[off];
    float res[4];
#pragma unroll
    for (int f = 0; f < 4; f++) {
      const float4* wp = (const float4*)(w2 + (((long)f * C_ + c) << 5));
      float dl = 0.f;
#pragma unroll
      for (int d4 = 0; d4 < 8; d4++) {
        float4 u = wp[d4];
        int db = (f << 5) + (d4 << 2);
        dl += mrow[db + 0] * u.x + mrow[db + 1] * u.y +
              mrow[db + 2] * u.z + mrow[db + 3] * u.w;
      }
      res[f] = xb + xxv * (tmaa[f * C_ + c] + dl);
    }
    xrg[off] = res[0]; xwa[off] = res[1]; xk[off] = res[2]; xv[off] = res[3];
  }
}

// ---------------- K5: stage-2 small GEMMs + gates + per-head kk norm --------
__global__ __launch_bounds__(256) void fuse2_kernel(
    const float* __restrict__ kraw, const float* __restrict__ w1b,
    const float* __restrict__ kk1, const float* __restrict__ a1,
    const float* __restrict__ ma1, const float* __restrict__ mk1,
    const float* __restrict__ dw2, const float* __restrict__ kkw2,
    const float* __restrict__ aw2, const float* __restrict__ maw2,
    const float* __restrict__ mkw2,
    const float* __restrict__ tdec, const float* __restrict__ taa,
    const float* __restrict__ tma, const float* __restrict__ tmk,
    float* __restrict__ ew, float* __restrict__ kfin,
    float* __restrict__ kkn, float* __restrict__ bbo) {
  int m = blockIdx.x, tid = threadIdx.x;
  __shared__ float w1r[64], kk1r[16], a1r[16], ma1r[16], mk1r[16];
  if (tid < 64) w1r[tid] = w1b[(long)m * 64 + tid];
  else if (tid < 80) kk1r[tid - 64] = kk1[(long)m * 16 + tid - 64];
  else if (tid < 96) a1r[tid - 80] = a1[(long)m * 16 + tid - 80];
  else if (tid < 112) ma1r[tid - 96] = ma1[(long)m * 16 + tid - 96];
  else if (tid < 128) mk1r[tid - 112] = mk1[(long)m * 16 + tid - 112];
  __syncthreads();
  float kkp[4], av[4], wv[4], kr[4], mkv[4];
  float sumsq = 0.f;
#pragma unroll
  for (int j = 0; j < 4; j++) {
    int c = (tid << 2) + j;
    long off = (long)m * C_ + c;
    float wd = 0.f;
    const float4* dp = (const float4*)(dw2 + ((long)c << 6));
#pragma unroll
    for (int d4 = 0; d4 < 16; d4++) {
      float4 u = dp[d4];
      int db = d4 << 2;
      wd += w1r[db + 0] * u.x + w1r[db + 1] * u.y +
            w1r[db + 2] * u.z + w1r[db + 3] * u.w;
    }
    float w = -softplusf_(-(tdec[c] + wd)) - 0.5f;
    wv[j] = w;
    float kd = 0.f, ad = 0.f, mad = 0.f, mkd = 0.f;
    const float4* kp = (const float4*)(kkw2 + ((long)c << 4));
    const float4* ap = (const float4*)(aw2 + ((long)c << 4));
    const float4* mp = (const float4*)(maw2 + ((long)c << 4));
    const float4* qp = (const float4*)(mkw2 + ((long)c << 4));
#pragma unroll
    for (int d4 = 0; d4 < 4; d4++) {
      float4 u1 = kp[d4], u2 = ap[d4], u3 = mp[d4], u4 = qp[d4];
      int db = d4 << 2;
      kd += kk1r[db + 0] * u1.x + kk1r[db + 1] * u1.y +
            kk1r[db + 2] * u1.z + kk1r[db + 3] * u1.w;
      ad += a1r[db + 0] * u2.x + a1r[db + 1] * u2.y +
            a1r[db + 2] * u2.z + a1r[db + 3] * u2.w;
      mad += ma1r[db + 0] * u3.x + ma1r[db + 1] * u3.y +
             ma1r[db + 2] * u3.z + ma1r[db + 3] * u3.w;
      mkd += mk1r[db + 0] * u4.x + mk1r[db + 1] * u4.y +
             mk1r[db + 2] * u4.z + mk1r[db + 3] * u4.w;
    }
    float krw = kraw[off];
    float kkpre = krw + kd;
    kkp[j] = kkpre;
    sumsq += kkpre * kkpre;
    float a = sigmoidf_(taa[c] + ad);
    av[j] = a;
    float ma = sigmoidf_(tma[c] + mad);
    float mk = sigmoidf_(tmk[c] + mkd);
    mkv[j] = mk;
    kr[j] = krw * (ma + a * (1.f - ma));
  }
  // per-head sumsq: 16 consecutive lanes cover one head (64 channels)
  sumsq += __shfl_xor(sumsq, 1);
  sumsq += __shfl_xor(sumsq, 2);
  sumsq += __shfl_xor(sumsq, 4);
  sumsq += __shfl_xor(sumsq, 8);
  float rn = 1.0f / fmaxf(sqrtf(sumsq), 1e-12f);
#pragma unroll
  for (int j = 0; j < 4; j++) {
    int c = (tid << 2) + j;
    long off = (long)m * C_ + c;
    float kknv = kkp[j] * rn;
    kkn[off] = kknv;
    bbo[off] = -kknv * av[j];
    ew[off] = expf(wv[j]);
    kfin[off] = kr[j] * expf(wv[j] * mkv[j]);
  }
}

// ---------------- K6: RWKV-7 scan. 256 blocks x 64 threads ------------------
// block -> (b,h, row-block of 8). lane = (g<<4)|q : rows row0+g / row0+4+g,
// q covers keys 4q..4q+3. Reductions: 4-level shfl_xor within 16-lane groups.
__global__ __launch_bounds__(64) void scan_kernel(
    const float* __restrict__ rB, const float* __restrict__ ewB,
    const float* __restrict__ kB, const float* __restrict__ vB,
    const float* __restrict__ kkB, const float* __restrict__ bbB,
    float* __restrict__ yB) {
  int bid = blockIdx.x;
  int bh = bid >> 3, rb = bid & 7;
  int b = bh >> 4, h = bh & 15;
  int lane = threadIdx.x;
  int g = lane >> 4, q = lane & 15;
  int row0 = rb << 3;
  int kq = q << 2;
  float S0[4] = {0, 0, 0, 0}, S1[4] = {0, 0, 0, 0};
  long off = ((long)b * T_) * C_ + (h << 6);
  float4 ckk = *(const float4*)(kkB + off + kq);
  float4 cr = *(const float4*)(rB + off + kq);
  float4 cew = *(const float4*)(ewB + off + kq);
  float4 ck = *(const float4*)(kB + off + kq);
  float4 cbb = *(const float4*)(bbB + off + kq);
  float cv0 = vB[off + row0 + g];
  float cv1 = vB[off + row0 + 4 + g];
  for (int t = 0; t < T_; t++) {
    long noff = (t < T_ - 1) ? off + C_ : off;
    float4 nkk = *(const float4*)(kkB + noff + kq);
    float4 nr = *(const float4*)(rB + noff + kq);
    float4 new_ = *(const float4*)(ewB + noff + kq);
    float4 nk = *(const float4*)(kB + noff + kq);
    float4 nbb = *(const float4*)(bbB + noff + kq);
    float nv0 = vB[noff + row0 + g];
    float nv1 = vB[noff + row0 + 4 + g];
    // pass 0 (row row0+g)
    float sab = S0[0] * ckk.x + S0[1] * ckk.y + S0[2] * ckk.z + S0[3] * ckk.w;
    sab += __shfl_xor(sab, 1); sab += __shfl_xor(sab, 2);
    sab += __shfl_xor(sab, 4); sab += __shfl_xor(sab, 8);
    S0[0] = S0[0] * cew.x + sab * cbb.x + cv0 * ck.x;
    S0[1] = S0[1] * cew.y + sab * cbb.y + cv0 * ck.y;
    S0[2] = S0[2] * cew.z + sab * cbb.z + cv0 * ck.z;
    S0[3] = S0[3] * cew.w + sab * cbb.w + cv0 * ck.w;
    float y0 = S0[0] * cr.x + S0[1] * cr.y + S0[2] * cr.z + S0[3] * cr.w;
    y0 += __shfl_xor(y0, 1); y0 += __shfl_xor(y0, 2);
    y0 += __shfl_xor(y0, 4); y0 += __shfl_xor(y0, 8);
    // pass 1 (row row0+4+g)
    float sab1 = S1[0] * ckk.x + S1[1] * ckk.y + S1[2] * ckk.z + S1[3] * ckk.w;
    sab1 += __shfl_xor(sab1, 1); sab1 += __shfl_xor(sab1, 2);
    sab1 += __shfl_xor(sab1, 4); sab1 += __shfl_xor(sab1, 8);
    S1[0] = S1[0] * cew.x + sab1 * cbb.x + cv1 * ck.x;
    S1[1] = S1[1] * cew.y + sab1 * cbb.y + cv1 * ck.y;
    S1[2] = S1[2] * cew.z + sab1 * cbb.z + cv1 * ck.z;
    S1[3] = S1[3] * cew.w + sab1 * cbb.w + cv1 * ck.w;
    float y1 = S1[0] * cr.x + S1[1] * cr.y + S1[2] * cr.z + S1[3] * cr.w;
    y1 += __shfl_xor(y1, 1); y1 += __shfl_xor(y1, 2);
    y1 += __shfl_xor(y1, 4); y1 += __shfl_xor(y1, 8);
    if (q == 0) {
      yB[off + row0 + g] = y0;
      yB[off + row0 + 4 + g] = y1;
    }
    ckk = nkk; cr = nr; cew = new_; ck = nk; cbb = nbb;
    cv0 = nv0; cv1 = nv1;
    off = noff;
  }
}

// ---------------- K7: GroupNorm + bonus + gate ------------------------------
__global__ __launch_bounds__(256) void gnout_kernel(
    const float* __restrict__ y, const float* __restrict__ r,
    const float* __restrict__ kf, const float* __restrict__ v,
    const float* __restrict__ g,
    const float* __restrict__ lnw, const float* __restrict__ lnb,
    const float* __restrict__ fa, float* __restrict__ z) {
  int tid = threadIdx.x;
  int w = tid >> 6, lane = tid & 63;
  int gi = (blockIdx.x << 2) + w;  // (b*T+t)*H + h
  int h = gi & 15, mt = gi >> 4;
  long off = (long)mt * C_ + (h << 6) + lane;
  float yv = y[off];
  float s = yv;
  s += __shfl_xor(s, 1); s += __shfl_xor(s, 2); s += __shfl_xor(s, 4);
  s += __shfl_xor(s, 8); s += __shfl_xor(s, 16); s += __shfl_xor(s, 32);
  float mu = s * (1.0f / 64.0f);
  float d = yv - mu;
  float s2 = d * d;
  s2 += __shfl_xor(s2, 1); s2 += __shfl_xor(s2, 2); s2 += __shfl_xor(s2, 4);
  s2 += __shfl_xor(s2, 8); s2 += __shfl_xor(s2, 16); s2 += __shfl_xor(s2, 32);
  float var = s2 * (1.0f / 64.0f);
  int hc = (h << 6) + lane;
  float dot = r[off] * kf[off] * fa[hc];
  dot += __shfl_xor(dot, 1); dot += __shfl_xor(dot, 2); dot += __shfl_xor(dot, 4);
  dot += __shfl_xor(dot, 8); dot += __shfl_xor(dot, 16); dot += __shfl_xor(dot, 32);
  float yn = d * rsqrtf(var + 0.00064f) * lnw[hc] + lnb[hc];
  z[off] = (yn + dot * v[off]) * g[off];
}

extern "C" void kernel_launch(void* const* d_in, const int* in_sizes, int n_in,
                              void* d_out, int out_size, void* d_ws, size_t ws_size,
                              hipStream_t stream) {
  const float* x = (const float*)d_in[0];
  const float* tmx = (const float*)d_in[1];
  const float* tmaa = (const float*)d_in[2];
  const float* tmw1 = (const float*)d_in[3];
  const float* tmw2 = (const float*)d_in[4];
  const float* tdec = (const float*)d_in[5];
  const float* tdw1 = (const float*)d_in[6];
  const float* tdw2 = (const float*)d_in[7];
  const float* taa5 = (const float*)d_in[8];
  const float* taw1 = (const float*)d_in[9];
  const float* taw2 = (const float*)d_in[10];
  const float* tkw1 = (const float*)d_in[11];
  const float* tkw2 = (const float*)d_in[12];
  const float* gw1 = (const float*)d_in[13];
  const float* gw2 = (const float*)d_in[14];
  const float* tmia = (const float*)d_in[15];
  const float* maw1 = (const float*)d_in[16];
  const float* maw2 = (const float*)d_in[17];
  const float* tmik = (const float*)d_in[18];
  const float* mkw1 = (const float*)d_in[19];
  const float* mkw2 = (const float*)d_in[20];
  const float* wrec = (const float*)d_in[21];
  const float* wkey = (const float*)d_in[22];
  const float* wval = (const float*)d_in[23];
  const float* wout = (const float*)d_in[24];
  const float* lnw = (const float*)d_in[25];
  const float* lnb = (const float*)d_in[26];
  const float* faaa = (const float*)d_in[27];

  const long MT = 2048, CC = 1024;
  float* p = (float*)d_ws;
  float* xx = p;  p += MT * CC;
  float* xxx = p; p += MT * CC;
  float* xrg = p; p += MT * CC;
  float* xwa = p; p += MT * CC;
  float* xk = p;  p += MT * CC;
  float* xv = p;  p += MT * CC;
  float* rr = p;  p += MT * CC;
  float* kraw = p; p += MT * CC;
  float* vv = p;  p += MT * CC;
  float* gg = p;  p += MT * CC;
  float* mix = p; p += MT * 128;
  float* g1 = p;  p += MT * 128;
  float* w1b = p; p += MT * 64;
  float* kk1 = p; p += MT * 16;
  float* a1 = p;  p += MT * 16;
  float* ma1 = p; p += MT * 16;
  float* mk1 = p; p += MT * 16;
  // dead-buffer reuse (verified non-overlapping in time):
  float* ew = xrg;    // xrg dead after rr/g1 GEMMs
  float* kfin = xwa;  // xwa dead after w1b/a1/ma1 GEMMs
  float* kkn = xk;    // xk dead after kraw/kk1/mk1 GEMMs
  float* bbo = xv;    // xv dead after vv GEMM
  float* y = xx;      // xx dead after mix4
  float* z = xxx;     // xxx dead after mix GEMM

  auto gemm = [&](const float* A, const float* W, float* Cf,
                  int M, int N, int K, int act) {
    dim3 grid((N + 63) / 64, M / 64);
    gemm_kernel<<<grid, 256, 0, stream>>>(A, W, Cf, M, N, K, act);
  };

  shift_kernel<<<8192, 256, 0, stream>>>(x, tmx, xx, xxx);
  gemm(xxx, tmw1, mix, 2048, 128, 1024, 1);
  mix4_kernel<<<2048, 256, 0, stream>>>(x, xx, mix, tmaa, tmw2, xrg, xwa, xk, xv);
  gemm(xrg, wrec, rr, 2048, 1024, 1024, 0);
  gemm(xrg, gw1, g1, 2048, 128, 1024, 1);
  gemm(g1, gw2, gg, 2048, 1024, 128, 0);
  gemm(xk, wkey, kraw, 2048, 1024, 1024, 0);
  gemm(xk, tkw1, kk1, 2048, 16, 1024, 1);
  gemm(xk, mkw1, mk1, 2048, 16, 1024, 0);
  gemm(xv, wval, vv, 2048, 1024, 1024, 0);
  gemm(xwa, tdw1, w1b, 2048, 64, 1024, 1);
  gemm(xwa, taw1, a1, 2048, 16, 1024, 0);
  gemm(xwa, maw1, ma1, 2048, 16, 1024, 0);
  fuse2_kernel<<<2048, 256, 0, stream>>>(kraw, w1b, kk1, a1, ma1, mk1,
                                         tdw2, tkw2, taw2, maw2, mkw2,
                                         tdec, taa5, tmia, tmik,
                                         ew, kfin, kkn, bbo);
  scan_kernel<<<256, 64, 0, stream>>>(rr, ew, kfin, vv, kkn, bbo, y);
  gnout_kernel<<<8192, 256, 0, stream>>>(y, rr, kfin, vv, gg, lnw, lnb, faaa, z);
  gemm(z, wout, (float*)d_out, 2048, 1024, 1024, 0);
}

// Round 4
// 1398.909 us; speedup vs baseline: 1.2611x; 1.2611x over previous
//
#include <hip/hip_runtime.h>
#include <hip/hip_bf16.h>

typedef __hip_bfloat16 bf16;

#define B_ 2
#define T_ 1024
#define C_ 1024
#define H_ 16
#define N_ 64

using short8 = __attribute__((ext_vector_type(8))) short;
using f32x4 = __attribute__((ext_vector_type(4))) float;

__device__ __forceinline__ float us2f(unsigned short u) {
  return __uint_as_float(((unsigned int)u) << 16);
}
__device__ __forceinline__ bf16 f2bf(float f) { return __float2bfloat16(f); }
__device__ __forceinline__ float sigmoidf_(float x) { return 1.0f / (1.0f + expf(-x)); }
__device__ __forceinline__ float softplusf_(float x) {
  return fmaxf(x, 0.0f) + log1pf(expf(-fabsf(x)));
}

// ---------------- K0: fused weight fp32->bf16 conversion --------------------
// ranges in float4 units: tmw1 32768 | wrec 262144 | gw1 32768 | gw2 32768 |
// wkey 262144 | wval 262144 | wout 262144  (total 1146880)
__global__ __launch_bounds__(256) void cvt_weights_kernel(
    const float* __restrict__ s0, const float* __restrict__ s1,
    const float* __restrict__ s2, const float* __restrict__ s3,
    const float* __restrict__ s4, const float* __restrict__ s5,
    const float* __restrict__ s6,
    bf16* __restrict__ d0, bf16* __restrict__ d1, bf16* __restrict__ d2,
    bf16* __restrict__ d3, bf16* __restrict__ d4, bf16* __restrict__ d5,
    bf16* __restrict__ d6) {
  long i4 = (long)blockIdx.x * 256 + threadIdx.x;
  const float* s; bf16* d; long off;
  if (i4 < 32768) { s = s0; d = d0; off = i4; }
  else if (i4 < 294912) { s = s1; d = d1; off = i4 - 32768; }
  else if (i4 < 327680) { s = s2; d = d2; off = i4 - 294912; }
  else if (i4 < 360448) { s = s3; d = d3; off = i4 - 327680; }
  else if (i4 < 622592) { s = s4; d = d4; off = i4 - 360448; }
  else if (i4 < 884736) { s = s5; d = d5; off = i4 - 622592; }
  else { s = s6; d = d6; off = i4 - 884736; }
  float4 v = *(const float4*)(s + off * 4);
  d[off * 4 + 0] = f2bf(v.x);
  d[off * 4 + 1] = f2bf(v.y);
  d[off * 4 + 2] = f2bf(v.z);
  d[off * 4 + 3] = f2bf(v.w);
}

// ---------------- K1: token shift (writes xx f32, xxx bf16) -----------------
__global__ __launch_bounds__(256) void shift_kernel(
    const float* __restrict__ x, const float* __restrict__ tmx,
    float* __restrict__ xx, bf16* __restrict__ xxxb) {
  long idx = (long)blockIdx.x * 256 + threadIdx.x;  // < B*T*C
  int c = (int)(idx & (C_ - 1));
  int t = (int)((idx >> 10) & (T_ - 1));
  float xv = x[idx];
  float xp = (t > 0) ? x[idx - C_] : 0.0f;
  float d = xp - xv;
  xx[idx] = d;
  xxxb[idx] = f2bf(xv + d * tmx[c]);
}

// ---------------- MFMA GEMM: C = A(bf16 MxK) * W^T (W bf16 NxK) -------------
// 64x64 block tile, 4 waves, each wave: 16 rows x 64 cols (4 acc tiles).
// act: 0 none, 1 tanh. Out fp32 (Cf) or bf16 (Cb).
__global__ __launch_bounds__(256) void gemm_mfma_kernel(
    const bf16* __restrict__ A, const bf16* __restrict__ W,
    float* __restrict__ Cf, bf16* __restrict__ Cb,
    int M, int N, int K, int act) {
  __shared__ __align__(16) bf16 As[64][40];  // 80B row stride: 16B-aligned b128
  __shared__ __align__(16) bf16 Ws[64][40];
  int tid = threadIdx.x;
  int m0 = blockIdx.y << 6, n0 = blockIdx.x << 6;
  int srow = tid >> 2, skg = (tid & 3) << 3;   // staging: row, k-offset (8 bf16)
  int wv = tid >> 6, lane = tid & 63;
  int fr = lane & 15, fq = lane >> 4;          // fragment row/col, k-quad
  f32x4 acc0 = {0.f, 0.f, 0.f, 0.f}, acc1 = acc0, acc2 = acc0, acc3 = acc0;
  const bf16* Ap = A + (long)(m0 + srow) * K + skg;
  const bf16* Wp = W + (long)(n0 + srow) * K + skg;
  for (int k0 = 0; k0 < K; k0 += 32) {
    *(short8*)&As[srow][skg] = *(const short8*)(Ap + k0);
    *(short8*)&Ws[srow][skg] = *(const short8*)(Wp + k0);
    __syncthreads();
    short8 af = *(const short8*)&As[(wv << 4) + fr][fq << 3];
    short8 b0 = *(const short8*)&Ws[fr][fq << 3];
    short8 b1 = *(const short8*)&Ws[16 + fr][fq << 3];
    short8 b2 = *(const short8*)&Ws[32 + fr][fq << 3];
    short8 b3 = *(const short8*)&Ws[48 + fr][fq << 3];
    acc0 = __builtin_amdgcn_mfma_f32_16x16x32_bf16(af, b0, acc0, 0, 0, 0);
    acc1 = __builtin_amdgcn_mfma_f32_16x16x32_bf16(af, b1, acc1, 0, 0, 0);
    acc2 = __builtin_amdgcn_mfma_f32_16x16x32_bf16(af, b2, acc2, 0, 0, 0);
    acc3 = __builtin_amdgcn_mfma_f32_16x16x32_bf16(af, b3, acc3, 0, 0, 0);
    __syncthreads();
  }
  // C/D layout: col = lane&15, row = (lane>>4)*4 + reg
  int orow = m0 + (wv << 4) + (fq << 2);
  int ocol = n0 + fr;
  f32x4 av[4] = {acc0, acc1, acc2, acc3};
#pragma unroll
  for (int nt = 0; nt < 4; nt++) {
#pragma unroll
    for (int r = 0; r < 4; r++) {
      float vvv = av[nt][r];
      if (act == 1) vvv = tanhf(vvv);
      long oi = (long)(orow + r) * N + ocol + (nt << 4);
      if (Cb) Cb[oi] = f2bf(vvv); else Cf[oi] = vvv;
    }
  }
}

// ---------------- small fp32 GEMM (N<=64): C = A(bf16) * W^T(fp32) ----------
__global__ __launch_bounds__(256) void gemm_kernel(
    const bf16* __restrict__ A, const float* __restrict__ W,
    float* __restrict__ Cf, int M, int N, int K, int act) {
  __shared__ __align__(16) float As[16][72];
  __shared__ __align__(16) float Ws[16][72];
  int tid = threadIdx.x;
  int tx = tid & 15, ty = tid >> 4;
  int m0 = blockIdx.y * 64, n0 = blockIdx.x * 64;
  int lr = tid >> 2;
  int lc = (tid & 3) << 2;
  float acc[4][4] = {};
  for (int k0 = 0; k0 < K; k0 += 16) {
    ushort4 ua = *(const ushort4*)(A + (long)(m0 + lr) * K + (k0 + lc));
    As[lc + 0][lr] = us2f(ua.x); As[lc + 1][lr] = us2f(ua.y);
    As[lc + 2][lr] = us2f(ua.z); As[lc + 3][lr] = us2f(ua.w);
    float4 wv = make_float4(0.f, 0.f, 0.f, 0.f);
    int wr = n0 + lr;
    if (wr < N) wv = *(const float4*)(W + (long)wr * K + (k0 + lc));
    Ws[lc + 0][lr] = wv.x; Ws[lc + 1][lr] = wv.y;
    Ws[lc + 2][lr] = wv.z; Ws[lc + 3][lr] = wv.w;
    __syncthreads();
#pragma unroll
    for (int kk = 0; kk < 16; kk++) {
      float4 a4 = *(const float4*)&As[kk][ty << 2];
      float4 b4 = *(const float4*)&Ws[kk][tx << 2];
      float aa[4] = {a4.x, a4.y, a4.z, a4.w};
      float bb[4] = {b4.x, b4.y, b4.z, b4.w};
#pragma unroll
      for (int i = 0; i < 4; i++) {
#pragma unroll
        for (int j = 0; j < 4; j++) acc[i][j] += aa[i] * bb[j];
      }
    }
    __syncthreads();
  }
#pragma unroll
  for (int i = 0; i < 4; i++) {
    int row = m0 + (ty << 2) + i;
#pragma unroll
    for (int j = 0; j < 4; j++) {
      int col = n0 + (tx << 2) + j;
      if (col < N) {
        float vv = acc[i][j];
        if (act == 1) vv = tanhf(vv);
        Cf[(long)row * N + col] = vv;
      }
    }
  }
}

// ---------------- K3: deltas + build xrg/xwa/xk/xv (bf16 out) ---------------
__global__ __launch_bounds__(256) void mix4_kernel(
    const float* __restrict__ x, const float* __restrict__ xx,
    const float* __restrict__ mix, const float* __restrict__ tmaa,
    const float* __restrict__ w2,
    bf16* __restrict__ xrg, bf16* __restrict__ xwa,
    bf16* __restrict__ xk, bf16* __restrict__ xv) {
  int m = blockIdx.x;
  int tid = threadIdx.x;
  __shared__ float mrow[128];
  if (tid < 128) mrow[tid] = mix[(long)m * 128 + tid];
  __syncthreads();
#pragma unroll
  for (int cc = 0; cc < 4; cc++) {
    int c = tid + (cc << 8);
    long off = (long)m * C_ + c;
    float xb = x[off];
    float xxv = xx[off];
    float res[4];
#pragma unroll
    for (int f = 0; f < 4; f++) {
      const float4* wp = (const float4*)(w2 + (((long)f * C_ + c) << 5));
      float dl = 0.f;
#pragma unroll
      for (int d4 = 0; d4 < 8; d4++) {
        float4 u = wp[d4];
        int db = (f << 5) + (d4 << 2);
        dl += mrow[db + 0] * u.x + mrow[db + 1] * u.y +
              mrow[db + 2] * u.z + mrow[db + 3] * u.w;
      }
      res[f] = xb + xxv * (tmaa[f * C_ + c] + dl);
    }
    xrg[off] = f2bf(res[0]); xwa[off] = f2bf(res[1]);
    xk[off] = f2bf(res[2]); xv[off] = f2bf(res[3]);
  }
}

// ---------------- K5: stage-2 small GEMMs + gates + per-head kk norm --------
__global__ __launch_bounds__(256) void fuse2_kernel(
    const float* __restrict__ kraw, const float* __restrict__ w1b,
    const float* __restrict__ kk1, const float* __restrict__ a1,
    const float* __restrict__ ma1, const float* __restrict__ mk1,
    const float* __restrict__ dw2, const float* __restrict__ kkw2,
    const float* __restrict__ aw2, const float* __restrict__ maw2,
    const float* __restrict__ mkw2,
    const float* __restrict__ tdec, const float* __restrict__ taa,
    const float* __restrict__ tma, const float* __restrict__ tmk,
    float* __restrict__ ew, float* __restrict__ kfin,
    float* __restrict__ kkn, float* __restrict__ bbo) {
  int m = blockIdx.x, tid = threadIdx.x;
  __shared__ float w1r[64], kk1r[16], a1r[16], ma1r[16], mk1r[16];
  if (tid < 64) w1r[tid] = w1b[(long)m * 64 + tid];
  else if (tid < 80) kk1r[tid - 64] = kk1[(long)m * 16 + tid - 64];
  else if (tid < 96) a1r[tid - 80] = a1[(long)m * 16 + tid - 80];
  else if (tid < 112) ma1r[tid - 96] = ma1[(long)m * 16 + tid - 96];
  else if (tid < 128) mk1r[tid - 112] = mk1[(long)m * 16 + tid - 112];
  __syncthreads();
  float kkp[4], av[4], wv[4], kr[4], mkv[4];
  float sumsq = 0.f;
#pragma unroll
  for (int j = 0; j < 4; j++) {
    int c = (tid << 2) + j;
    long off = (long)m * C_ + c;
    float wd = 0.f;
    const float4* dp = (const float4*)(dw2 + ((long)c << 6));
#pragma unroll
    for (int d4 = 0; d4 < 16; d4++) {
      float4 u = dp[d4];
      int db = d4 << 2;
      wd += w1r[db + 0] * u.x + w1r[db + 1] * u.y +
            w1r[db + 2] * u.z + w1r[db + 3] * u.w;
    }
    float w = -softplusf_(-(tdec[c] + wd)) - 0.5f;
    wv[j] = w;
    float kd = 0.f, ad = 0.f, mad = 0.f, mkd = 0.f;
    const float4* kp = (const float4*)(kkw2 + ((long)c << 4));
    const float4* ap = (const float4*)(aw2 + ((long)c << 4));
    const float4* mp = (const float4*)(maw2 + ((long)c << 4));
    const float4* qp = (const float4*)(mkw2 + ((long)c << 4));
#pragma unroll
    for (int d4 = 0; d4 < 4; d4++) {
      float4 u1 = kp[d4], u2 = ap[d4], u3 = mp[d4], u4 = qp[d4];
      int db = d4 << 2;
      kd += kk1r[db + 0] * u1.x + kk1r[db + 1] * u1.y +
            kk1r[db + 2] * u1.z + kk1r[db + 3] * u1.w;
      ad += a1r[db + 0] * u2.x + a1r[db + 1] * u2.y +
            a1r[db + 2] * u2.z + a1r[db + 3] * u2.w;
      mad += ma1r[db + 0] * u3.x + ma1r[db + 1] * u3.y +
             ma1r[db + 2] * u3.z + ma1r[db + 3] * u3.w;
      mkd += mk1r[db + 0] * u4.x + mk1r[db + 1] * u4.y +
             mk1r[db + 2] * u4.z + mk1r[db + 3] * u4.w;
    }
    float krw = kraw[off];
    float kkpre = krw + kd;
    kkp[j] = kkpre;
    sumsq += kkpre * kkpre;
    float a = sigmoidf_(taa[c] + ad);
    av[j] = a;
    float ma = sigmoidf_(tma[c] + mad);
    float mk = sigmoidf_(tmk[c] + mkd);
    mkv[j] = mk;
    kr[j] = krw * (ma + a * (1.f - ma));
  }
  sumsq += __shfl_xor(sumsq, 1);
  sumsq += __shfl_xor(sumsq, 2);
  sumsq += __shfl_xor(sumsq, 4);
  sumsq += __shfl_xor(sumsq, 8);
  float rn = 1.0f / fmaxf(sqrtf(sumsq), 1e-12f);
#pragma unroll
  for (int j = 0; j < 4; j++) {
    int c = (tid << 2) + j;
    long off = (long)m * C_ + c;
    float kknv = kkp[j] * rn;
    kkn[off] = kknv;
    bbo[off] = -kknv * av[j];
    ew[off] = expf(wv[j]);
    kfin[off] = kr[j] * expf(wv[j] * mkv[j]);
  }
}

// ---------------- K6: RWKV-7 scan, depth-4 register prefetch ----------------
__global__ __launch_bounds__(64) void scan_kernel(
    const float* __restrict__ rB, const float* __restrict__ ewB,
    const float* __restrict__ kB, const float* __restrict__ vB,
    const float* __restrict__ kkB, const float* __restrict__ bbB,
    float* __restrict__ yB) {
  int bid = blockIdx.x;
  int bh = bid >> 3, rb = bid & 7;
  int b = bh >> 4, h = bh & 15;
  int lane = threadIdx.x;
  int g = lane >> 4, q = lane & 15;
  int row0 = rb << 3;
  int kq = q << 2;
  float S0[4] = {0, 0, 0, 0}, S1[4] = {0, 0, 0, 0};
  const long base = ((long)b * T_) * C_ + (h << 6);
  float4 skk[4], sr[4], sew[4], sk[4], sbb[4];
  float sv0[4], sv1[4];
#pragma unroll
  for (int i = 0; i < 4; i++) {
    long o = base + (long)i * C_;
    skk[i] = *(const float4*)(kkB + o + kq);
    sr[i] = *(const float4*)(rB + o + kq);
    sew[i] = *(const float4*)(ewB + o + kq);
    sk[i] = *(const float4*)(kB + o + kq);
    sbb[i] = *(const float4*)(bbB + o + kq);
    sv0[i] = vB[o + row0 + g];
    sv1[i] = vB[o + row0 + 4 + g];
  }
  for (int t = 0; t < T_; t += 4) {
#pragma unroll
    for (int i = 0; i < 4; i++) {
      int tt = t + i;
      float4 ckk = skk[i], cr = sr[i], cew = sew[i], ck = sk[i], cbb = sbb[i];
      float cv0 = sv0[i], cv1 = sv1[i];
      int tl = tt + 4; if (tl > T_ - 1) tl = T_ - 1;
      long o = base + (long)tl * C_;
      skk[i] = *(const float4*)(kkB + o + kq);
      sr[i] = *(const float4*)(rB + o + kq);
      sew[i] = *(const float4*)(ewB + o + kq);
      sk[i] = *(const float4*)(kB + o + kq);
      sbb[i] = *(const float4*)(bbB + o + kq);
      sv0[i] = vB[o + row0 + g];
      sv1[i] = vB[o + row0 + 4 + g];
      // pass 0 (row row0+g)
      float sab = S0[0] * ckk.x + S0[1] * ckk.y + S0[2] * ckk.z + S0[3] * ckk.w;
      sab += __shfl_xor(sab, 1); sab += __shfl_xor(sab, 2);
      sab += __shfl_xor(sab, 4); sab += __shfl_xor(sab, 8);
      S0[0] = S0[0] * cew.x + sab * cbb.x + cv0 * ck.x;
      S0[1] = S0[1] * cew.y + sab * cbb.y + cv0 * ck.y;
      S0[2] = S0[2] * cew.z + sab * cbb.z + cv0 * ck.z;
      S0[3] = S0[3] * cew.w + sab * cbb.w + cv0 * ck.w;
      float y0 = S0[0] * cr.x + S0[1] * cr.y + S0[2] * cr.z + S0[3] * cr.w;
      y0 += __shfl_xor(y0, 1); y0 += __shfl_xor(y0, 2);
      y0 += __shfl_xor(y0, 4); y0 += __shfl_xor(y0, 8);
      // pass 1 (row row0+4+g)
      float sab1 = S1[0] * ckk.x + S1[1] * ckk.y + S1[2] * ckk.z + S1[3] * ckk.w;
      sab1 += __shfl_xor(sab1, 1); sab1 += __shfl_xor(sab1, 2);
      sab1 += __shfl_xor(sab1, 4); sab1 += __shfl_xor(sab1, 8);
      S1[0] = S1[0] * cew.x + sab1 * cbb.x + cv1 * ck.x;
      S1[1] = S1[1] * cew.y + sab1 * cbb.y + cv1 * ck.y;
      S1[2] = S1[2] * cew.z + sab1 * cbb.z + cv1 * ck.z;
      S1[3] = S1[3] * cew.w + sab1 * cbb.w + cv1 * ck.w;
      float y1 = S1[0] * cr.x + S1[1] * cr.y + S1[2] * cr.z + S1[3] * cr.w;
      y1 += __shfl_xor(y1, 1); y1 += __shfl_xor(y1, 2);
      y1 += __shfl_xor(y1, 4); y1 += __shfl_xor(y1, 8);
      if (q == 0) {
        long yo = base + (long)tt * C_;
        yB[yo + row0 + g] = y0;
        yB[yo + row0 + 4 + g] = y1;
      }
    }
  }
}

// ---------------- K7: GroupNorm + bonus + gate (bf16 out) -------------------
__global__ __launch_bounds__(256) void gnout_kernel(
    const float* __restrict__ y, const float* __restrict__ r,
    const float* __restrict__ kf, const float* __restrict__ v,
    const float* __restrict__ g,
    const float* __restrict__ lnw, const float* __restrict__ lnb,
    const float* __restrict__ fa, bf16* __restrict__ z) {
  int tid = threadIdx.x;
  int w = tid >> 6, lane = tid & 63;
  int gi = (blockIdx.x << 2) + w;  // (b*T+t)*H + h
  int h = gi & 15, mt = gi >> 4;
  long off = (long)mt * C_ + (h << 6) + lane;
  float yv = y[off];
  float s = yv;
  s += __shfl_xor(s, 1); s += __shfl_xor(s, 2); s += __shfl_xor(s, 4);
  s += __shfl_xor(s, 8); s += __shfl_xor(s, 16); s += __shfl_xor(s, 32);
  float mu = s * (1.0f / 64.0f);
  float d = yv - mu;
  float s2 = d * d;
  s2 += __shfl_xor(s2, 1); s2 += __shfl_xor(s2, 2); s2 += __shfl_xor(s2, 4);
  s2 += __shfl_xor(s2, 8); s2 += __shfl_xor(s2, 16); s2 += __shfl_xor(s2, 32);
  float var = s2 * (1.0f / 64.0f);
  int hc = (h << 6) + lane;
  float dot = r[off] * kf[off] * fa[hc];
  dot += __shfl_xor(dot, 1); dot += __shfl_xor(dot, 2); dot += __shfl_xor(dot, 4);
  dot += __shfl_xor(dot, 8); dot += __shfl_xor(dot, 16); dot += __shfl_xor(dot, 32);
  float yn = d * rsqrtf(var + 0.00064f) * lnw[hc] + lnb[hc];
  z[off] = f2bf((yn + dot * v[off]) * g[off]);
}

extern "C" void kernel_launch(void* const* d_in, const int* in_sizes, int n_in,
                              void* d_out, int out_size, void* d_ws, size_t ws_size,
                              hipStream_t stream) {
  const float* x = (const float*)d_in[0];
  const float* tmx = (const float*)d_in[1];
  const float* tmaa = (const float*)d_in[2];
  const float* tmw1 = (const float*)d_in[3];
  const float* tmw2 = (const float*)d_in[4];
  const float* tdec = (const float*)d_in[5];
  const float* tdw1 = (const float*)d_in[6];
  const float* tdw2 = (const float*)d_in[7];
  const float* taa5 = (const float*)d_in[8];
  const float* taw1 = (const float*)d_in[9];
  const float* taw2 = (const float*)d_in[10];
  const float* tkw1 = (const float*)d_in[11];
  const float* tkw2 = (const float*)d_in[12];
  const float* gw1 = (const float*)d_in[13];
  const float* gw2 = (const float*)d_in[14];
  const float* tmia = (const float*)d_in[15];
  const float* maw1 = (const float*)d_in[16];
  const float* maw2 = (const float*)d_in[17];
  const float* tmik = (const float*)d_in[18];
  const float* mkw1 = (const float*)d_in[19];
  const float* mkw2 = (const float*)d_in[20];
  const float* wrec = (const float*)d_in[21];
  const float* wkey = (const float*)d_in[22];
  const float* wval = (const float*)d_in[23];
  const float* wout = (const float*)d_in[24];
  const float* lnw = (const float*)d_in[25];
  const float* lnb = (const float*)d_in[26];
  const float* faaa = (const float*)d_in[27];

  const long MT = 2048, CC = 1024;
  char* base = (char*)d_ws;
  float* xx = (float*)base;    base += MT * CC * 4;   // also y
  bf16* xxxb = (bf16*)base;    base += MT * CC * 2;
  bf16* xrgb = (bf16*)base;    base += MT * CC * 2;   // ┐ kfin overlays (8MB)
  bf16* xwab = (bf16*)base;    base += MT * CC * 2;   // ┘
  bf16* xkb = (bf16*)base;     base += MT * CC * 2;   // ┐ kkn overlays (8MB)
  bf16* xvb = (bf16*)base;     base += MT * CC * 2;   // ┘
  float* rr = (float*)base;    base += MT * CC * 4;
  float* kraw = (float*)base;  base += MT * CC * 4;   // also ew
  float* vv = (float*)base;    base += MT * CC * 4;
  float* gg = (float*)base;    base += MT * CC * 4;
  float* bbo = (float*)base;   base += MT * CC * 4;
  float* mix = (float*)base;   base += MT * 128 * 4;
  bf16* g1b = (bf16*)base;     base += MT * 128 * 2;
  float* w1b = (float*)base;   base += MT * 64 * 4;
  float* kk1 = (float*)base;   base += MT * 16 * 4;
  float* a1 = (float*)base;    base += MT * 16 * 4;
  float* ma1 = (float*)base;   base += MT * 16 * 4;
  float* mk1 = (float*)base;   base += MT * 16 * 4;
  bf16* zb = (bf16*)base;      base += MT * CC * 2;
  bf16* tmw1b = (bf16*)base;   base += 128 * CC * 2;
  bf16* wrecb = (bf16*)base;   base += CC * CC * 2;
  bf16* gw1b = (bf16*)base;    base += 128 * CC * 2;
  bf16* gw2b = (bf16*)base;    base += CC * 128 * 2;
  bf16* wkeyb = (bf16*)base;   base += CC * CC * 2;
  bf16* wvalb = (bf16*)base;   base += CC * CC * 2;
  bf16* woutb = (bf16*)base;   base += CC * CC * 2;
  // aliases (dead-buffer reuse, verified non-overlapping in time):
  float* ew = kraw;            // fuse2 reads kraw then writes ew at same offs
  float* kfin = (float*)xrgb;  // xrg/xwa bf16 dead before fuse2
  float* kkn = (float*)xkb;    // xk/xv bf16 dead before fuse2
  float* y = xx;               // xx dead after mix4

  auto gemm_m = [&](const bf16* A, const bf16* W, float* Cf, bf16* Cb,
                    int M, int N, int K, int act) {
    dim3 grid(N / 64, M / 64);
    gemm_mfma_kernel<<<grid, 256, 0, stream>>>(A, W, Cf, Cb, M, N, K, act);
  };
  auto gemm_s = [&](const bf16* A, const float* W, float* Cf,
                    int M, int N, int K, int act) {
    dim3 grid((N + 63) / 64, M / 64);
    gemm_kernel<<<grid, 256, 0, stream>>>(A, W, Cf, M, N, K, act);
  };

  cvt_weights_kernel<<<4480, 256, 0, stream>>>(
      tmw1, wrec, gw1, gw2, wkey, wval, wout,
      tmw1b, wrecb, gw1b, gw2b, wkeyb, wvalb, woutb);
  shift_kernel<<<8192, 256, 0, stream>>>(x, tmx, xx, xxxb);
  gemm_m(xxxb, tmw1b, mix, nullptr, 2048, 128, 1024, 1);
  mix4_kernel<<<2048, 256, 0, stream>>>(x, xx, mix, tmaa, tmw2,
                                        xrgb, xwab, xkb, xvb);
  gemm_m(xrgb, wrecb, rr, nullptr, 2048, 1024, 1024, 0);
  gemm_m(xrgb, gw1b, nullptr, g1b, 2048, 128, 1024, 1);
  gemm_m(g1b, gw2b, gg, nullptr, 2048, 1024, 128, 0);
  gemm_m(xkb, wkeyb, kraw, nullptr, 2048, 1024, 1024, 0);
  gemm_s(xkb, tkw1, kk1, 2048, 16, 1024, 1);
  gemm_s(xkb, mkw1, mk1, 2048, 16, 1024, 0);
  gemm_m(xvb, wvalb, vv, nullptr, 2048, 1024, 1024, 0);
  gemm_s(xwab, tdw1, w1b, 2048, 64, 1024, 1);
  gemm_s(xwab, taw1, a1, 2048, 16, 1024, 0);
  gemm_s(xwab, maw1, ma1, 2048, 16, 1024, 0);
  fuse2_kernel<<<2048, 256, 0, stream>>>(kraw, w1b, kk1, a1, ma1, mk1,
                                         tdw2, tkw2, taw2, maw2, mkw2,
                                         tdec, taa5, tmia, tmik,
                                         ew, kfin, kkn, bbo);
  scan_kernel<<<256, 64, 0, stream>>>(rr, ew, kfin, vv, kkn, bbo, y);
  gnout_kernel<<<8192, 256, 0, stream>>>(y, rr, kfin, vv, gg, lnw, lnb, faaa, zb);
  gemm_m(zb, woutb, (float*)d_out, nullptr, 2048, 1024, 1024, 0);
}